// Round 2
// 706.943 us; speedup vs baseline: 1.5697x; 1.5697x over previous
//
#include <hip/hip_runtime.h>
#include <hip/hip_bf16.h>
#include <stdint.h>

// WindowAttention block for MI355X (gfx950). Round 9 (= round 8 resubmit;
// round-8 bench died in the container broker with no measurement).
// Round-7 confirmed: inputs fp32, OUTPUT fp32. Pipeline unchanged except:
// attn_naive_kernel (448 us, MfmaUtil=0, latency-bound scalar dots) replaced
// by attn_mfma_kernel: fused per-window MFMA QK^T -> wave-parallel softmax ->
// MFMA PV with LDS-transposed V chunks. Expected ~30 us (HBM-bound).
// ws peak 123,744,256 B (<= 130 MB).

typedef __attribute__((ext_vector_type(4))) float f32x4;
typedef __attribute__((ext_vector_type(8))) short bf16x8;
typedef __attribute__((ext_vector_type(4))) short bf16x4;

__device__ __forceinline__ void async_cp16(const void* g, void* l) {
    __builtin_amdgcn_global_load_lds(
        (const __attribute__((address_space(1))) void*)g,
        (__attribute__((address_space(3))) void*)l,
        16, 0, 0);
}

__device__ __forceinline__ short f2bf(float f) {
    __hip_bfloat16 h = __float2bfloat16(f);
    return __builtin_bit_cast(short, h);
}
__device__ __forceinline__ float bf2f(short s) {
    return __bfloat162float(__builtin_bit_cast(__hip_bfloat16, s));
}

// ------------- GEMM: C[MxN] = A[MxK] * Bt[NxK]^T + bias -------------------
// A, Bt bf16. MODE 0: C bf16 (+bias, optional RELU). MODE 1: C fp32 (+bias).
// MODE 2: C fp32 += acc (accumulate in place; each block touches own tile).
template <int RELU, int MODE>
__global__ __launch_bounds__(256, 2) void gemm_kernel(
    const short* __restrict__ A, int lda,
    const short* __restrict__ Bt, int ldb,
    const float* __restrict__ bias,
    void* __restrict__ Cv, int ldc,
    int M, int N, int K)
{
    __shared__ __align__(16) short lds[8192]; // At[128][32] | Bts[128][32]
    short* At  = lds;
    short* Bts = lds + 4096;

    const int t = threadIdx.x;
    const int wave = t >> 6, lane = t & 63;
    const int quad = lane >> 4, l16 = lane & 15;
    const int wx = wave & 1, wy = wave >> 1;
    const long m0 = (long)blockIdx.x * 128;
    const long n0 = (long)blockIdx.y * 128;

    const int sr = t >> 2;           // staging row 0..63
    const int sc = (t & 3) << 3;     // staging col 0,8,16,24

    const short* ga = A  + (m0 + sr) * (long)lda + sc;
    const short* gb = Bt + (n0 + sr) * (long)ldb + sc;
    short* la0 = At  + wave * 512;          // wave-uniform LDS bases
    short* la1 = At  + 2048 + wave * 512;
    short* lb0 = Bts + wave * 512;
    short* lb1 = Bts + 2048 + wave * 512;

    f32x4 acc[4][4] = {};

    for (int k0 = 0; k0 < K; k0 += 32) {
        async_cp16(ga + k0,                  la0);
        async_cp16(ga + (long)64 * lda + k0, la1);
        async_cp16(gb + k0,                  lb0);
        async_cp16(gb + (long)64 * ldb + k0, lb1);
        __syncthreads();

        bf16x8 af[4], bfr[4];
#pragma unroll
        for (int i = 0; i < 4; ++i)
            af[i] = *(const bf16x8*)(At + (wy * 64 + i * 16 + l16) * 32 + quad * 8);
#pragma unroll
        for (int i = 0; i < 4; ++i)
            bfr[i] = *(const bf16x8*)(Bts + (wx * 64 + i * 16 + l16) * 32 + quad * 8);
#pragma unroll
        for (int mi = 0; mi < 4; ++mi)
#pragma unroll
            for (int ni = 0; ni < 4; ++ni)
                acc[mi][ni] = __builtin_amdgcn_mfma_f32_16x16x32_bf16(
                    af[mi], bfr[ni], acc[mi][ni], 0, 0, 0);
        __syncthreads();
    }

#pragma unroll
    for (int mi = 0; mi < 4; ++mi) {
#pragma unroll
        for (int ni = 0; ni < 4; ++ni) {
            const int n = (int)n0 + wx * 64 + ni * 16 + l16;
            const float bv = (MODE == 2) ? 0.f : bias[n];
#pragma unroll
            for (int r = 0; r < 4; ++r) {
                const long m = m0 + wy * 64 + mi * 16 + quad * 4 + r;
                float v = acc[mi][ni][r] + bv;
                if (MODE == 0) {
                    if (RELU) v = fmaxf(v, 0.f);
                    ((short*)Cv)[m * ldc + n] = f2bf(v);
                } else if (MODE == 1) {
                    ((float*)Cv)[m * ldc + n] = v;
                } else {
                    ((float*)Cv)[m * ldc + n] += v;   // own element, race-free
                }
            }
        }
    }
}

// -------- MFMA windowed attention: one block (4 waves) per 64-token window -
// QKV: M x 3072 bf16 (Q|K|V). O: M x 1024 bf16.
// Phase A: S = Q.K^T * scale via mfma (wave = 32x32 quadrant, frags straight
//          from global, 1-deep register prefetch) -> Sf fp32 LDS.
// Phase B: softmax, 4 threads/row, width-4 shfl reduce -> Pb bf16 LDS.
// Phase C: O = P.V via mfma; V staged per 256-col chunk into LDS transposed
//          (Vt[e][tok], tok-group XOR swizzle to dodge write bank conflicts).
__global__ __launch_bounds__(256) void attn_mfma_kernel(
    const short* __restrict__ QKV, short* __restrict__ O)
{
    __shared__ __align__(16) float Sf[64 * 65];    // 16640 B
    __shared__ __align__(16) short Pb[64 * 72];    //  9216 B
    __shared__ __align__(16) short Vt[256 * 72];   // 36864 B   (tot 62720)

    const int t = threadIdx.x;
    const int wave = t >> 6, lane = t & 63;
    const int quad = lane >> 4, l16 = lane & 15;
    const long rowbase = (long)blockIdx.x * 64;
    const short* Qg = QKV + rowbase * 3072;
    const short* Kg = Qg + 1024;
    const short* Vg = Qg + 2048;

    // ---------------- phase A: scores ----------------
    {
        const int wy = wave >> 1, wx = wave & 1;
        const short* qp0 = Qg + (long)(wy * 32 + l16) * 3072 + quad * 8;
        const short* qp1 = qp0 + 16 * 3072;
        const short* kp0 = Kg + (long)(wx * 32 + l16) * 3072 + quad * 8;
        const short* kp1 = kp0 + 16 * 3072;

        f32x4 s00 = {}, s01 = {}, s10 = {}, s11 = {};
        bf16x8 a0 = *(const bf16x8*)qp0;
        bf16x8 a1 = *(const bf16x8*)qp1;
        bf16x8 b0 = *(const bf16x8*)kp0;
        bf16x8 b1 = *(const bf16x8*)kp1;

#pragma unroll 2
        for (int k0 = 0; k0 < 1024; k0 += 32) {
            const int kn = (k0 + 32 < 1024) ? k0 + 32 : 0;  // clamp (dummy reload)
            bf16x8 na0 = *(const bf16x8*)(qp0 + kn);
            bf16x8 na1 = *(const bf16x8*)(qp1 + kn);
            bf16x8 nb0 = *(const bf16x8*)(kp0 + kn);
            bf16x8 nb1 = *(const bf16x8*)(kp1 + kn);
            s00 = __builtin_amdgcn_mfma_f32_16x16x32_bf16(a0, b0, s00, 0, 0, 0);
            s01 = __builtin_amdgcn_mfma_f32_16x16x32_bf16(a0, b1, s01, 0, 0, 0);
            s10 = __builtin_amdgcn_mfma_f32_16x16x32_bf16(a1, b0, s10, 0, 0, 0);
            s11 = __builtin_amdgcn_mfma_f32_16x16x32_bf16(a1, b1, s11, 0, 0, 0);
            a0 = na0; a1 = na1; b0 = nb0; b1 = nb1;
        }

        // C/D layout: row = quad*4 + r, col = l16
        const int rb = wy * 32 + quad * 4;
        const int cb = wx * 32 + l16;
#pragma unroll
        for (int r = 0; r < 4; ++r) {
            Sf[(rb + r) * 65 + cb]           = s00[r] * 0.03125f;
            Sf[(rb + r) * 65 + cb + 16]      = s01[r] * 0.03125f;
            Sf[(rb + 16 + r) * 65 + cb]      = s10[r] * 0.03125f;
            Sf[(rb + 16 + r) * 65 + cb + 16] = s11[r] * 0.03125f;
        }
    }
    __syncthreads();

    // ---------------- phase B: softmax (4 threads per row) ----------------
    {
        const int row = t >> 2;
        const int cs = (t & 3) * 16;
        const float* sp = Sf + row * 65 + cs;
        float v[16];
        float mx = -1e30f;
#pragma unroll
        for (int j = 0; j < 16; ++j) { v[j] = sp[j]; mx = fmaxf(mx, v[j]); }
        mx = fmaxf(mx, __shfl_xor(mx, 1, 64));
        mx = fmaxf(mx, __shfl_xor(mx, 2, 64));
        float sum = 0.f;
#pragma unroll
        for (int j = 0; j < 16; ++j) { v[j] = __expf(v[j] - mx); sum += v[j]; }
        sum += __shfl_xor(sum, 1, 64);
        sum += __shfl_xor(sum, 2, 64);
        const float inv = 1.f / sum;
        short* pp = Pb + row * 72 + cs;
        bf16x8 o0, o1;
#pragma unroll
        for (int j = 0; j < 8; ++j) { o0[j] = f2bf(v[j] * inv); o1[j] = f2bf(v[8 + j] * inv); }
        *(bf16x8*)(pp) = o0;
        *(bf16x8*)(pp + 8) = o1;
    }
    __syncthreads();

    // ---------------- phase C: O = P.V, 256-col chunks ----------------
    // P fragments (same for every chunk): Pb[mi*16+l16][ki*32 + quad*8 ..+7]
    bf16x8 am[2][4];
#pragma unroll
    for (int ki = 0; ki < 2; ++ki)
#pragma unroll
        for (int mi = 0; mi < 4; ++mi)
            am[ki][mi] = *(const bf16x8*)(Pb + (mi * 16 + l16) * 72 + ki * 32 + quad * 8);

    for (int nc = 0; nc < 4; ++nc) {
        const int nbase = nc * 256;
        // stage V[:, nbase..nbase+255] transposed -> Vt[e_local][tok]
#pragma unroll
        for (int it = 0; it < 8; ++it) {
            const int idx = it * 256 + t;          // 0..2047
            const int tok = idx >> 5;              // 0..63
            const int grp = idx & 31;              // e-group of 8
            bf16x8 v = *(const bf16x8*)(Vg + (long)tok * 3072 + nbase + grp * 8);
            const int tsw = tok ^ ((grp & 7) << 3);  // bank swizzle
            short* dst = Vt + (grp * 8) * 72 + tsw;
#pragma unroll
            for (int j = 0; j < 8; ++j) dst[j * 72] = v[j];
        }
        __syncthreads();

        f32x4 acc[4][4] = {};
#pragma unroll
        for (int ki = 0; ki < 2; ++ki) {
            bf16x8 bn[4];
#pragma unroll
            for (int ni = 0; ni < 4; ++ni) {
                const int e_local = wave * 64 + ni * 16 + l16;
                const int s = (e_local >> 3) & 7;
                bn[ni] = *(const bf16x8*)(Vt + e_local * 72 + ((ki * 32 + quad * 8) ^ (s << 3)));
            }
#pragma unroll
            for (int mi = 0; mi < 4; ++mi)
#pragma unroll
                for (int ni = 0; ni < 4; ++ni)
                    acc[mi][ni] = __builtin_amdgcn_mfma_f32_16x16x32_bf16(
                        am[ki][mi], bn[ni], acc[mi][ni], 0, 0, 0);
        }

#pragma unroll
        for (int mi = 0; mi < 4; ++mi)
#pragma unroll
            for (int ni = 0; ni < 4; ++ni) {
                const long n = nbase + wave * 64 + ni * 16 + l16;
#pragma unroll
                for (int r = 0; r < 4; ++r) {
                    const long m = rowbase + mi * 16 + quad * 4 + r;
                    O[m * 1024 + n] = f2bf(acc[mi][ni][r]);
                }
            }
        __syncthreads();   // Vt reused next chunk
    }
}

// ------------- LN1: x1 = LN(x_fp32 + O_bf16) * g + b -> bf16 --------------
__global__ __launch_bounds__(256, 4) void ln1_kernel(
    const float* __restrict__ X, const short* __restrict__ R,
    const float* __restrict__ gamma, const float* __restrict__ beta,
    short* __restrict__ Y)
{
    __shared__ float red[8];
    const int t = threadIdx.x;
    const int wave = t >> 6, lane = t & 63;
    const long row = blockIdx.x;

    f32x4 xv = *(const f32x4*)(X + row * 1024 + t * 4);
    bf16x4 rv = *(const bf16x4*)(R + row * 1024 + t * 4);
    float v[4];
    float s = 0.f, sq = 0.f;
#pragma unroll
    for (int i = 0; i < 4; ++i) {
        v[i] = xv[i] + bf2f(rv[i]);
        s += v[i];
        sq += v[i] * v[i];
    }
#pragma unroll
    for (int off = 32; off > 0; off >>= 1) {
        s  += __shfl_down(s, off, 64);
        sq += __shfl_down(sq, off, 64);
    }
    if (lane == 0) { red[wave] = s; red[4 + wave] = sq; }
    __syncthreads();
    if (t == 0) {
        float S = red[0] + red[1] + red[2] + red[3];
        float Q = red[4] + red[5] + red[6] + red[7];
        float mean = S * (1.f / 1024.f);
        float var = fmaxf(Q * (1.f / 1024.f) - mean * mean, 0.f);
        red[0] = mean;
        red[1] = rsqrtf(var + 1e-5f);
    }
    __syncthreads();
    const float mean = red[0], rstd = red[1];
    f32x4 gv = *(const f32x4*)(gamma + t * 4);
    f32x4 bv = *(const f32x4*)(beta + t * 4);
    bf16x4 yv;
#pragma unroll
    for (int i = 0; i < 4; ++i)
        yv[i] = f2bf((v[i] - mean) * rstd * gv[i] + bv[i]);
    *(bf16x4*)(Y + row * 1024 + t * 4) = yv;
}

// ------ LN2: out = LN(x1_bf16 + F_fp32) * g + b -> fp32, in place on F ----
__global__ __launch_bounds__(256, 4) void ln2_kernel(
    const short* __restrict__ X1, float* __restrict__ F,
    const float* __restrict__ gamma, const float* __restrict__ beta)
{
    __shared__ float red[8];
    const int t = threadIdx.x;
    const int wave = t >> 6, lane = t & 63;
    const long row = blockIdx.x;

    bf16x4 xv = *(const bf16x4*)(X1 + row * 1024 + t * 4);
    f32x4 fv = *(const f32x4*)(F + row * 1024 + t * 4);
    float v[4];
    float s = 0.f, sq = 0.f;
#pragma unroll
    for (int i = 0; i < 4; ++i) {
        v[i] = bf2f(xv[i]) + fv[i];
        s += v[i];
        sq += v[i] * v[i];
    }
#pragma unroll
    for (int off = 32; off > 0; off >>= 1) {
        s  += __shfl_down(s, off, 64);
        sq += __shfl_down(sq, off, 64);
    }
    if (lane == 0) { red[wave] = s; red[4 + wave] = sq; }
    __syncthreads();
    if (t == 0) {
        float S = red[0] + red[1] + red[2] + red[3];
        float Q = red[4] + red[5] + red[6] + red[7];
        float mean = S * (1.f / 1024.f);
        float var = fmaxf(Q * (1.f / 1024.f) - mean * mean, 0.f);
        red[0] = mean;
        red[1] = rsqrtf(var + 1e-5f);
    }
    __syncthreads();
    const float mean = red[0], rstd = red[1];
    f32x4 gv = *(const f32x4*)(gamma + t * 4);
    f32x4 bv = *(const f32x4*)(beta + t * 4);
    f32x4 yv;
#pragma unroll
    for (int i = 0; i < 4; ++i)
        yv[i] = (v[i] - mean) * rstd * gv[i] + bv[i];
    *(f32x4*)(F + row * 1024 + t * 4) = yv;   // own row: in-place safe
}

// --------- weight transpose + cast: W[KxN] fp32 -> WT[NxK] bf16 -----------
__global__ __launch_bounds__(256, 2) void transpose_kernel(
    const float* __restrict__ W, short* __restrict__ WT, int K, int N)
{
    __shared__ __align__(16) short tile[64 * 72];
    const int t = threadIdx.x;
    const long kb = (long)blockIdx.x * 64, nb = (long)blockIdx.y * 64;
    const int r = t >> 3, c = (t & 7) << 3;
#pragma unroll
    for (int i = 0; i < 2; ++i) {
        f32x4 v0 = *(const f32x4*)(W + (kb + r + i * 32) * N + nb + c);
        f32x4 v1 = *(const f32x4*)(W + (kb + r + i * 32) * N + nb + c + 4);
        short* dst = tile + (r + i * 32) * 72 + c;
#pragma unroll
        for (int j = 0; j < 4; ++j) { dst[j] = f2bf(v0[j]); dst[4 + j] = f2bf(v1[j]); }
    }
    __syncthreads();
#pragma unroll
    for (int i = 0; i < 2; ++i) {
        const int rr = r + i * 32;      // n-index within tile
        bf16x8 o;
#pragma unroll
        for (int j = 0; j < 8; ++j) o[j] = tile[(c + j) * 72 + rr];
        *(bf16x8*)(WT + (nb + rr) * K + kb + c) = o;
    }
}

// --------------- x fp32 -> bf16 (into d_out lower half) -------------------
__global__ __launch_bounds__(256, 4) void cvt_kernel(
    const float* __restrict__ X, short* __restrict__ Y)
{
    const long i = ((long)blockIdx.x * 256 + threadIdx.x) * 4;
    f32x4 v = *(const f32x4*)(X + i);
    bf16x4 o;
#pragma unroll
    for (int j = 0; j < 4; ++j) o[j] = f2bf(v[j]);
    *(bf16x4*)(Y + i) = o;
}

__global__ void concat_bias_kernel(const float* __restrict__ bq,
                                   const float* __restrict__ bk,
                                   const float* __restrict__ bv,
                                   float* __restrict__ out)
{
    const int i = blockIdx.x * 256 + threadIdx.x;   // 0..3071
    float v;
    if (i < 1024)      v = bq[i];
    else if (i < 2048) v = bk[i - 1024];
    else               v = bv[i - 2048];
    out[i] = v;
}

extern "C" void kernel_launch(void* const* d_in, const int* in_sizes, int n_in,
                              void* d_out, int out_size, void* d_ws, size_t ws_size,
                              hipStream_t stream)
{
    const float* x   = (const float*)d_in[0];
    const float* Wq  = (const float*)d_in[1];
    const float* bq  = (const float*)d_in[2];
    const float* Wk  = (const float*)d_in[3];
    const float* bk  = (const float*)d_in[4];
    const float* Wv  = (const float*)d_in[5];
    const float* bv  = (const float*)d_in[6];
    const float* g1  = (const float*)d_in[7];
    const float* be1 = (const float*)d_in[8];
    const float* W1  = (const float*)d_in[9];
    const float* b1  = (const float*)d_in[10];
    const float* W2  = (const float*)d_in[11];
    const float* b2  = (const float*)d_in[12];
    const float* g2  = (const float*)d_in[13];
    const float* be2 = (const float*)d_in[14];

    const int M = in_sizes[0] / 1024;        // 16384 tokens
    float* F    = (float*)d_out;             // fp32 pre-LN2 sum & final out (64 MB)
    short* xbf  = (short*)d_out;             // bf16 x, lower 32 MB (dead after QKV)
    short* Obf  = (short*)d_out + (size_t)M * 1024;  // bf16 attn O, upper 32 MB

    // workspace layout (bytes); peak 123,744,256
    char* ws = (char*)d_ws;
    short* WqkvT = (short*)ws;                     // [0, 6291456)
    short* W1T   = (short*)(ws + 6291456);         // [.., 14680064)
    short* W2T   = (short*)(ws + 14680064);        // [.., 23068672)
    float* bqkv  = (float*)(ws + 23068672);        // [.., 23080960)
    short* QKV   = (short*)(ws + 23080960);        // M x 3072 bf16 (96 MB)
    short* Hh    = (short*)(ws + 23080960);        // M x 2048 bf16, overlays QKV[0:64MB)
    short* x1    = (short*)(ws + 23080960 + (size_t)M * 2048 * 2); // M x 1024 bf16, QKV[64:96MB)

    dim3 blk(256);
    // weight prep (fp32 -> transposed bf16)
    transpose_kernel<<<dim3(16, 16), blk, 0, stream>>>(Wq, WqkvT,               1024, 1024);
    transpose_kernel<<<dim3(16, 16), blk, 0, stream>>>(Wk, WqkvT + 1024 * 1024, 1024, 1024);
    transpose_kernel<<<dim3(16, 16), blk, 0, stream>>>(Wv, WqkvT + 2048 * 1024, 1024, 1024);
    transpose_kernel<<<dim3(16, 64), blk, 0, stream>>>(W1, W1T, 1024, 4096);
    transpose_kernel<<<dim3(64, 16), blk, 0, stream>>>(W2, W2T, 4096, 1024);
    concat_bias_kernel<<<12, blk, 0, stream>>>(bq, bk, bv, bqkv);
    cvt_kernel<<<M, blk, 0, stream>>>(x, xbf);

    // QKV = x_bf @ Wqkv + bqkv  (bf16 out)
    gemm_kernel<0, 0><<<dim3(M / 128, 24), blk, 0, stream>>>(
        xbf, 1024, WqkvT, 1024, bqkv, QKV, 3072, M, 3072, 1024);
    // windowed attention (MFMA) -> O (d_out upper half; xbf now dead)
    attn_mfma_kernel<<<M / 64, blk, 0, stream>>>(QKV, Obf);
    // x1 = LN(x + O) -> bf16 in ws (QKV dead from here)
    ln1_kernel<<<M, blk, 0, stream>>>(x, Obf, g1, be1, x1);
    // FFN half a: Hh = relu(x1 @ W1[:, :2048]); F = Hh @ W2[:2048, :] + b2 (fp32)
    gemm_kernel<1, 0><<<dim3(M / 128, 16), blk, 0, stream>>>(
        x1, 1024, W1T, 1024, b1, Hh, 2048, M, 2048, 1024);
    gemm_kernel<0, 1><<<dim3(M / 128, 8), blk, 0, stream>>>(
        Hh, 2048, W2T, 4096, b2, F, 1024, M, 1024, 2048);
    // FFN half b: Hh = relu(x1 @ W1[:, 2048:]); F += Hh @ W2[2048:, :]
    gemm_kernel<1, 0><<<dim3(M / 128, 16), blk, 0, stream>>>(
        x1, 1024, W1T + 2048 * 1024, 1024, b1 + 2048, Hh, 2048, M, 2048, 1024);
    gemm_kernel<0, 2><<<dim3(M / 128, 8), blk, 0, stream>>>(
        Hh, 2048, W2T + 2048, 4096, b2, F, 1024, M, 1024, 2048);
    // out = LN(x1 + F) -> fp32, in place on F (= d_out)
    ln2_kernel<<<M, blk, 0, stream>>>(x1, F, g2, be2);
}

// Round 3
// 676.257 us; speedup vs baseline: 1.6409x; 1.0454x over previous
//
#include <hip/hip_runtime.h>
#include <hip/hip_bf16.h>
#include <stdint.h>

// WindowAttention block for MI355X (gfx950). Round 10.
// Round-9 confirmed: MFMA attention = ~30us (off top-5); GEMMs now dominate
// (QKV 131us = 782 TF = m97-structure ceiling; MfmaUtil 34%, 1.26e7 bank conf).
// This round: 256x256/BK64/8-wave phase-interleaved GEMM (T2+T3+T4+T5):
// counted vmcnt(4) gates (no drain), per-phase half-tile prefetch, XOR-swizzled
// LDS (inverse-swizzled global src for linear global_load_lds dest), setprio
// around MFMA clusters. 128KB LDS, 1 block/CU.
// ws peak 123,744,256 B (<= 130 MB).

typedef __attribute__((ext_vector_type(4))) float f32x4;
typedef __attribute__((ext_vector_type(8))) short bf16x8;
typedef __attribute__((ext_vector_type(4))) short bf16x4;

__device__ __forceinline__ void async_cp16(const void* g, void* l) {
    __builtin_amdgcn_global_load_lds(
        (const __attribute__((address_space(1))) void*)g,
        (__attribute__((address_space(3))) void*)l,
        16, 0, 0);
}

__device__ __forceinline__ short f2bf(float f) {
    __hip_bfloat16 h = __float2bfloat16(f);
    return __builtin_bit_cast(short, h);
}
__device__ __forceinline__ float bf2f(short s) {
    return __bfloat162float(__builtin_bit_cast(__hip_bfloat16, s));
}

// ---------------- 256x256 8-wave phase-interleaved GEMM -------------------
// C[MxN] = A[MxK] * Bt[NxK]^T + bias. A, Bt bf16.
// MODE 0: C bf16 (+bias, optional RELU). MODE 1: C fp32 (+bias).
// MODE 2: C fp32 += acc.
// LDS (shorts): buf c at c*32768; A slab ksub at +ksub*8192 (256 rows x 32),
// B at +16384 likewise. Swizzle: short addr = (row*32 + quad*8) ^ ((row&7)<<3)
// (XOR spans granule bits AND row bit0 -> bijective per 8-row stripe).
// Staging: linear global_load_lds dest; global source inverse-swizzled:
// storage (srow,sg) holds logical row = srow ^ ((srow>>2)&1), g = sg ^ (row&3).
template <int RELU, int MODE>
__global__ __launch_bounds__(512, 2) void gemm256_kernel(
    const short* __restrict__ A, int lda,
    const short* __restrict__ Bt, int ldb,
    const float* __restrict__ bias,
    void* __restrict__ Cv, int ldc,
    int M, int N, int K)
{
    __shared__ __align__(16) short lds[65536];   // 128 KB

    const int t = threadIdx.x;
    const int wave = t >> 6, lane = t & 63;
    const int quad = lane >> 4, l16 = lane & 15;
    const int wm = wave >> 2, wn = wave & 3;      // 2 x 4 wave grid
    const long m0 = (long)blockIdx.x * 256;
    const long n0 = (long)blockIdx.y * 256;

    // staging constants (inverse swizzle baked into the global source)
    const int srow = t >> 2;                      // 0..127
    const int sg = t & 3;
    const int lr0 = srow ^ ((srow >> 2) & 1);     // logical row, j=0 block
    const int lg0 = sg ^ (lr0 & 3);               // logical granule (same for j=1)
    const short* gA = A + (m0 + lr0) * (long)lda + lg0 * 8;
    const short* gB = Bt + (n0 + lr0) * (long)ldb + lg0 * 8;
    const int wdst = wave * 512;                  // shorts, + j*4096

    // swizzled LDS read offsets (shorts, within a k-slab)
    int offA[8], offB[4];
#pragma unroll
    for (int mf = 0; mf < 8; ++mf) {
        const int row = wm * 128 + mf * 16 + l16;
        offA[mf] = (row * 32 + quad * 8) ^ ((row & 7) << 3);
    }
#pragma unroll
    for (int nf = 0; nf < 4; ++nf) {
        const int row = wn * 64 + nf * 16 + l16;
        offB[nf] = (row * 32 + quad * 8) ^ ((row & 7) << 3);
    }

    f32x4 acc[8][4] = {};
    const int NT = K >> 6;

#define STAGE_A(ksub, kt, buf)                                                 \
    do {                                                                       \
        const int ko_ = (kt) * 64 + (ksub) * 32;                               \
        short* d_ = lds + (buf) * 32768 + (ksub) * 8192 + wdst;                \
        async_cp16(gA + ko_, d_);                                              \
        async_cp16(gA + 128 * (long)lda + ko_, d_ + 4096);                     \
    } while (0)
#define STAGE_B(ksub, kt, buf)                                                 \
    do {                                                                       \
        const int ko_ = (kt) * 64 + (ksub) * 32;                               \
        short* d_ = lds + (buf) * 32768 + 16384 + (ksub) * 8192 + wdst;        \
        async_cp16(gB + ko_, d_);                                              \
        async_cp16(gB + 128 * (long)ldb + ko_, d_ + 4096);                     \
    } while (0)

    // prologue: stage tile 0 fully; gate on first two halves (A-k0, B-k0)
    STAGE_A(0, 0, 0); STAGE_B(0, 0, 0); STAGE_A(1, 0, 0); STAGE_B(1, 0, 0);
    asm volatile("s_waitcnt vmcnt(4)" ::: "memory");
    __builtin_amdgcn_s_barrier();
    __builtin_amdgcn_sched_barrier(0);

    for (int kt = 0; kt < NT; ++kt) {
        const int cbuf = kt & 1, nbuf = cbuf ^ 1;
        const short* Ab = lds + cbuf * 32768;
        const short* Bb = Ab + 16384;
        const bool more = (kt + 1 < NT);

        bf16x8 av[4], bv[4];

        // ===== phase 1: ksub0, mf 0-3 =====
#pragma unroll
        for (int nf = 0; nf < 4; ++nf) bv[nf] = *(const bf16x8*)(Bb + offB[nf]);
#pragma unroll
        for (int i = 0; i < 4; ++i) av[i] = *(const bf16x8*)(Ab + offA[i]);
        if (more) STAGE_A(0, kt + 1, nbuf);
        __builtin_amdgcn_sched_barrier(0);
        __builtin_amdgcn_s_barrier();
        asm volatile("s_waitcnt lgkmcnt(0)" ::: "memory");
        __builtin_amdgcn_sched_barrier(0);
        __builtin_amdgcn_s_setprio(1);
#pragma unroll
        for (int i = 0; i < 4; ++i)
#pragma unroll
            for (int nf = 0; nf < 4; ++nf)
                acc[i][nf] = __builtin_amdgcn_mfma_f32_16x16x32_bf16(
                    av[i], bv[nf], acc[i][nf], 0, 0, 0);
        __builtin_amdgcn_s_setprio(0);
        __builtin_amdgcn_sched_barrier(0);
        __builtin_amdgcn_s_barrier();

        // ===== phase 2: ksub0, mf 4-7 =====
#pragma unroll
        for (int i = 0; i < 4; ++i) av[i] = *(const bf16x8*)(Ab + offA[4 + i]);
        if (more) STAGE_B(0, kt + 1, nbuf);
        __builtin_amdgcn_sched_barrier(0);
        __builtin_amdgcn_s_barrier();
        asm volatile("s_waitcnt lgkmcnt(0)" ::: "memory");
        __builtin_amdgcn_sched_barrier(0);
        __builtin_amdgcn_s_setprio(1);
#pragma unroll
        for (int i = 0; i < 4; ++i)
#pragma unroll
            for (int nf = 0; nf < 4; ++nf)
                acc[4 + i][nf] = __builtin_amdgcn_mfma_f32_16x16x32_bf16(
                    av[i], bv[nf], acc[4 + i][nf], 0, 0, 0);
        __builtin_amdgcn_s_setprio(0);
        __builtin_amdgcn_sched_barrier(0);
        // mid gate: tile kt's k1 halves must be landed (newer in flight: k0' of kt+1)
        if (kt == NT - 1) asm volatile("s_waitcnt vmcnt(0)" ::: "memory");
        else              asm volatile("s_waitcnt vmcnt(4)" ::: "memory");
        __builtin_amdgcn_s_barrier();
        __builtin_amdgcn_sched_barrier(0);

        // ===== phase 3: ksub1, mf 0-3 =====
#pragma unroll
        for (int nf = 0; nf < 4; ++nf) bv[nf] = *(const bf16x8*)(Bb + 8192 + offB[nf]);
#pragma unroll
        for (int i = 0; i < 4; ++i) av[i] = *(const bf16x8*)(Ab + 8192 + offA[i]);
        if (more) STAGE_A(1, kt + 1, nbuf);
        __builtin_amdgcn_sched_barrier(0);
        __builtin_amdgcn_s_barrier();
        asm volatile("s_waitcnt lgkmcnt(0)" ::: "memory");
        __builtin_amdgcn_sched_barrier(0);
        __builtin_amdgcn_s_setprio(1);
#pragma unroll
        for (int i = 0; i < 4; ++i)
#pragma unroll
            for (int nf = 0; nf < 4; ++nf)
                acc[i][nf] = __builtin_amdgcn_mfma_f32_16x16x32_bf16(
                    av[i], bv[nf], acc[i][nf], 0, 0, 0);
        __builtin_amdgcn_s_setprio(0);
        __builtin_amdgcn_sched_barrier(0);
        __builtin_amdgcn_s_barrier();

        // ===== phase 4: ksub1, mf 4-7 =====
#pragma unroll
        for (int i = 0; i < 4; ++i) av[i] = *(const bf16x8*)(Ab + 8192 + offA[4 + i]);
        if (more) STAGE_B(1, kt + 1, nbuf);
        __builtin_amdgcn_sched_barrier(0);
        __builtin_amdgcn_s_barrier();
        asm volatile("s_waitcnt lgkmcnt(0)" ::: "memory");
        __builtin_amdgcn_sched_barrier(0);
        __builtin_amdgcn_s_setprio(1);
#pragma unroll
        for (int i = 0; i < 4; ++i)
#pragma unroll
            for (int nf = 0; nf < 4; ++nf)
                acc[4 + i][nf] = __builtin_amdgcn_mfma_f32_16x16x32_bf16(
                    av[i], bv[nf], acc[4 + i][nf], 0, 0, 0);
        __builtin_amdgcn_s_setprio(0);
        __builtin_amdgcn_sched_barrier(0);
        // end gate: next tile's k0 halves landed (newer in flight: its k1 halves)
        if (kt < NT - 1) asm volatile("s_waitcnt vmcnt(4)" ::: "memory");
        __builtin_amdgcn_s_barrier();
        __builtin_amdgcn_sched_barrier(0);
    }
#undef STAGE_A
#undef STAGE_B

    // epilogue
#pragma unroll
    for (int mf = 0; mf < 8; ++mf) {
#pragma unroll
        for (int nf = 0; nf < 4; ++nf) {
            const int n = (int)n0 + wn * 64 + nf * 16 + l16;
            const float bz = (MODE == 2) ? 0.f : bias[n];
#pragma unroll
            for (int r = 0; r < 4; ++r) {
                const long m = m0 + wm * 128 + mf * 16 + quad * 4 + r;
                float v = acc[mf][nf][r] + bz;
                if (MODE == 0) {
                    if (RELU) v = fmaxf(v, 0.f);
                    ((short*)Cv)[m * ldc + n] = f2bf(v);
                } else if (MODE == 1) {
                    ((float*)Cv)[m * ldc + n] = v;
                } else {
                    ((float*)Cv)[m * ldc + n] += v;   // own element, race-free
                }
            }
        }
    }
}

// -------- MFMA windowed attention: one block (4 waves) per 64-token window -
__global__ __launch_bounds__(256) void attn_mfma_kernel(
    const short* __restrict__ QKV, short* __restrict__ O)
{
    __shared__ __align__(16) float Sf[64 * 65];    // 16640 B
    __shared__ __align__(16) short Pb[64 * 72];    //  9216 B
    __shared__ __align__(16) short Vt[256 * 72];   // 36864 B   (tot 62720)

    const int t = threadIdx.x;
    const int wave = t >> 6, lane = t & 63;
    const int quad = lane >> 4, l16 = lane & 15;
    const long rowbase = (long)blockIdx.x * 64;
    const short* Qg = QKV + rowbase * 3072;
    const short* Kg = Qg + 1024;
    const short* Vg = Qg + 2048;

    // ---------------- phase A: scores ----------------
    {
        const int wy = wave >> 1, wx = wave & 1;
        const short* qp0 = Qg + (long)(wy * 32 + l16) * 3072 + quad * 8;
        const short* qp1 = qp0 + 16 * 3072;
        const short* kp0 = Kg + (long)(wx * 32 + l16) * 3072 + quad * 8;
        const short* kp1 = kp0 + 16 * 3072;

        f32x4 s00 = {}, s01 = {}, s10 = {}, s11 = {};
        bf16x8 a0 = *(const bf16x8*)qp0;
        bf16x8 a1 = *(const bf16x8*)qp1;
        bf16x8 b0 = *(const bf16x8*)kp0;
        bf16x8 b1 = *(const bf16x8*)kp1;

#pragma unroll 2
        for (int k0 = 0; k0 < 1024; k0 += 32) {
            const int kn = (k0 + 32 < 1024) ? k0 + 32 : 0;  // clamp (dummy reload)
            bf16x8 na0 = *(const bf16x8*)(qp0 + kn);
            bf16x8 na1 = *(const bf16x8*)(qp1 + kn);
            bf16x8 nb0 = *(const bf16x8*)(kp0 + kn);
            bf16x8 nb1 = *(const bf16x8*)(kp1 + kn);
            s00 = __builtin_amdgcn_mfma_f32_16x16x32_bf16(a0, b0, s00, 0, 0, 0);
            s01 = __builtin_amdgcn_mfma_f32_16x16x32_bf16(a0, b1, s01, 0, 0, 0);
            s10 = __builtin_amdgcn_mfma_f32_16x16x32_bf16(a1, b0, s10, 0, 0, 0);
            s11 = __builtin_amdgcn_mfma_f32_16x16x32_bf16(a1, b1, s11, 0, 0, 0);
            a0 = na0; a1 = na1; b0 = nb0; b1 = nb1;
        }

        const int rb = wy * 32 + quad * 4;
        const int cb = wx * 32 + l16;
#pragma unroll
        for (int r = 0; r < 4; ++r) {
            Sf[(rb + r) * 65 + cb]           = s00[r] * 0.03125f;
            Sf[(rb + r) * 65 + cb + 16]      = s01[r] * 0.03125f;
            Sf[(rb + 16 + r) * 65 + cb]      = s10[r] * 0.03125f;
            Sf[(rb + 16 + r) * 65 + cb + 16] = s11[r] * 0.03125f;
        }
    }
    __syncthreads();

    // ---------------- phase B: softmax (4 threads per row) ----------------
    {
        const int row = t >> 2;
        const int cs = (t & 3) * 16;
        const float* sp = Sf + row * 65 + cs;
        float v[16];
        float mx = -1e30f;
#pragma unroll
        for (int j = 0; j < 16; ++j) { v[j] = sp[j]; mx = fmaxf(mx, v[j]); }
        mx = fmaxf(mx, __shfl_xor(mx, 1, 64));
        mx = fmaxf(mx, __shfl_xor(mx, 2, 64));
        float sum = 0.f;
#pragma unroll
        for (int j = 0; j < 16; ++j) { v[j] = __expf(v[j] - mx); sum += v[j]; }
        sum += __shfl_xor(sum, 1, 64);
        sum += __shfl_xor(sum, 2, 64);
        const float inv = 1.f / sum;
        short* pp = Pb + row * 72 + cs;
        bf16x8 o0, o1;
#pragma unroll
        for (int j = 0; j < 8; ++j) { o0[j] = f2bf(v[j] * inv); o1[j] = f2bf(v[8 + j] * inv); }
        *(bf16x8*)(pp) = o0;
        *(bf16x8*)(pp + 8) = o1;
    }
    __syncthreads();

    // ---------------- phase C: O = P.V, 256-col chunks ----------------
    bf16x8 am[2][4];
#pragma unroll
    for (int ki = 0; ki < 2; ++ki)
#pragma unroll
        for (int mi = 0; mi < 4; ++mi)
            am[ki][mi] = *(const bf16x8*)(Pb + (mi * 16 + l16) * 72 + ki * 32 + quad * 8);

    for (int nc = 0; nc < 4; ++nc) {
        const int nbase = nc * 256;
#pragma unroll
        for (int it = 0; it < 8; ++it) {
            const int idx = it * 256 + t;          // 0..2047
            const int tok = idx >> 5;              // 0..63
            const int grp = idx & 31;              // e-group of 8
            bf16x8 v = *(const bf16x8*)(Vg + (long)tok * 3072 + nbase + grp * 8);
            const int tsw = tok ^ ((grp & 7) << 3);  // bank swizzle
            short* dst = Vt + (grp * 8) * 72 + tsw;
#pragma unroll
            for (int j = 0; j < 8; ++j) dst[j * 72] = v[j];
        }
        __syncthreads();

        f32x4 acc[4][4] = {};
#pragma unroll
        for (int ki = 0; ki < 2; ++ki) {
            bf16x8 bn[4];
#pragma unroll
            for (int ni = 0; ni < 4; ++ni) {
                const int e_local = wave * 64 + ni * 16 + l16;
                const int s = (e_local >> 3) & 7;
                bn[ni] = *(const bf16x8*)(Vt + e_local * 72 + ((ki * 32 + quad * 8) ^ (s << 3)));
            }
#pragma unroll
            for (int mi = 0; mi < 4; ++mi)
#pragma unroll
                for (int ni = 0; ni < 4; ++ni)
                    acc[mi][ni] = __builtin_amdgcn_mfma_f32_16x16x32_bf16(
                        am[ki][mi], bn[ni], acc[mi][ni], 0, 0, 0);
        }

#pragma unroll
        for (int mi = 0; mi < 4; ++mi)
#pragma unroll
            for (int ni = 0; ni < 4; ++ni) {
                const long n = nbase + wave * 64 + ni * 16 + l16;
#pragma unroll
                for (int r = 0; r < 4; ++r) {
                    const long m = rowbase + mi * 16 + quad * 4 + r;
                    O[m * 1024 + n] = f2bf(acc[mi][ni][r]);
                }
            }
        __syncthreads();   // Vt reused next chunk
    }
}

// ------------- LN1: x1 = LN(x_fp32 + O_bf16) * g + b -> bf16 --------------
__global__ __launch_bounds__(256, 4) void ln1_kernel(
    const float* __restrict__ X, const short* __restrict__ R,
    const float* __restrict__ gamma, const float* __restrict__ beta,
    short* __restrict__ Y)
{
    __shared__ float red[8];
    const int t = threadIdx.x;
    const int wave = t >> 6, lane = t & 63;
    const long row = blockIdx.x;

    f32x4 xv = *(const f32x4*)(X + row * 1024 + t * 4);
    bf16x4 rv = *(const bf16x4*)(R + row * 1024 + t * 4);
    float v[4];
    float s = 0.f, sq = 0.f;
#pragma unroll
    for (int i = 0; i < 4; ++i) {
        v[i] = xv[i] + bf2f(rv[i]);
        s += v[i];
        sq += v[i] * v[i];
    }
#pragma unroll
    for (int off = 32; off > 0; off >>= 1) {
        s  += __shfl_down(s, off, 64);
        sq += __shfl_down(sq, off, 64);
    }
    if (lane == 0) { red[wave] = s; red[4 + wave] = sq; }
    __syncthreads();
    if (t == 0) {
        float S = red[0] + red[1] + red[2] + red[3];
        float Q = red[4] + red[5] + red[6] + red[7];
        float mean = S * (1.f / 1024.f);
        float var = fmaxf(Q * (1.f / 1024.f) - mean * mean, 0.f);
        red[0] = mean;
        red[1] = rsqrtf(var + 1e-5f);
    }
    __syncthreads();
    const float mean = red[0], rstd = red[1];
    f32x4 gv = *(const f32x4*)(gamma + t * 4);
    f32x4 bv = *(const f32x4*)(beta + t * 4);
    bf16x4 yv;
#pragma unroll
    for (int i = 0; i < 4; ++i)
        yv[i] = f2bf((v[i] - mean) * rstd * gv[i] + bv[i]);
    *(bf16x4*)(Y + row * 1024 + t * 4) = yv;
}

// ------ LN2: out = LN(x1_bf16 + F_fp32) * g + b -> fp32, in place on F ----
__global__ __launch_bounds__(256, 4) void ln2_kernel(
    const short* __restrict__ X1, float* __restrict__ F,
    const float* __restrict__ gamma, const float* __restrict__ beta)
{
    __shared__ float red[8];
    const int t = threadIdx.x;
    const int wave = t >> 6, lane = t & 63;
    const long row = blockIdx.x;

    bf16x4 xv = *(const bf16x4*)(X1 + row * 1024 + t * 4);
    f32x4 fv = *(const f32x4*)(F + row * 1024 + t * 4);
    float v[4];
    float s = 0.f, sq = 0.f;
#pragma unroll
    for (int i = 0; i < 4; ++i) {
        v[i] = bf2f(xv[i]) + fv[i];
        s += v[i];
        sq += v[i] * v[i];
    }
#pragma unroll
    for (int off = 32; off > 0; off >>= 1) {
        s  += __shfl_down(s, off, 64);
        sq += __shfl_down(sq, off, 64);
    }
    if (lane == 0) { red[wave] = s; red[4 + wave] = sq; }
    __syncthreads();
    if (t == 0) {
        float S = red[0] + red[1] + red[2] + red[3];
        float Q = red[4] + red[5] + red[6] + red[7];
        float mean = S * (1.f / 1024.f);
        float var = fmaxf(Q * (1.f / 1024.f) - mean * mean, 0.f);
        red[0] = mean;
        red[1] = rsqrtf(var + 1e-5f);
    }
    __syncthreads();
    const float mean = red[0], rstd = red[1];
    f32x4 gv = *(const f32x4*)(gamma + t * 4);
    f32x4 bv = *(const f32x4*)(beta + t * 4);
    f32x4 yv;
#pragma unroll
    for (int i = 0; i < 4; ++i)
        yv[i] = (v[i] - mean) * rstd * gv[i] + bv[i];
    *(f32x4*)(F + row * 1024 + t * 4) = yv;   // own row: in-place safe
}

// --------- weight transpose + cast: W[KxN] fp32 -> WT[NxK] bf16 -----------
__global__ __launch_bounds__(256, 2) void transpose_kernel(
    const float* __restrict__ W, short* __restrict__ WT, int K, int N)
{
    __shared__ __align__(16) short tile[64 * 72];
    const int t = threadIdx.x;
    const long kb = (long)blockIdx.x * 64, nb = (long)blockIdx.y * 64;
    const int r = t >> 3, c = (t & 7) << 3;
#pragma unroll
    for (int i = 0; i < 2; ++i) {
        f32x4 v0 = *(const f32x4*)(W + (kb + r + i * 32) * N + nb + c);
        f32x4 v1 = *(const f32x4*)(W + (kb + r + i * 32) * N + nb + c + 4);
        short* dst = tile + (r + i * 32) * 72 + c;
#pragma unroll
        for (int j = 0; j < 4; ++j) { dst[j] = f2bf(v0[j]); dst[4 + j] = f2bf(v1[j]); }
    }
    __syncthreads();
#pragma unroll
    for (int i = 0; i < 2; ++i) {
        const int rr = r + i * 32;      // n-index within tile
        bf16x8 o;
#pragma unroll
        for (int j = 0; j < 8; ++j) o[j] = tile[(c + j) * 72 + rr];
        *(bf16x8*)(WT + (nb + rr) * K + kb + c) = o;
    }
}

// --------------- x fp32 -> bf16 (into d_out lower half) -------------------
__global__ __launch_bounds__(256, 4) void cvt_kernel(
    const float* __restrict__ X, short* __restrict__ Y)
{
    const long i = ((long)blockIdx.x * 256 + threadIdx.x) * 4;
    f32x4 v = *(const f32x4*)(X + i);
    bf16x4 o;
#pragma unroll
    for (int j = 0; j < 4; ++j) o[j] = f2bf(v[j]);
    *(bf16x4*)(Y + i) = o;
}

__global__ void concat_bias_kernel(const float* __restrict__ bq,
                                   const float* __restrict__ bk,
                                   const float* __restrict__ bv,
                                   float* __restrict__ out)
{
    const int i = blockIdx.x * 256 + threadIdx.x;   // 0..3071
    float v;
    if (i < 1024)      v = bq[i];
    else if (i < 2048) v = bk[i - 1024];
    else               v = bv[i - 2048];
    out[i] = v;
}

extern "C" void kernel_launch(void* const* d_in, const int* in_sizes, int n_in,
                              void* d_out, int out_size, void* d_ws, size_t ws_size,
                              hipStream_t stream)
{
    const float* x   = (const float*)d_in[0];
    const float* Wq  = (const float*)d_in[1];
    const float* bq  = (const float*)d_in[2];
    const float* Wk  = (const float*)d_in[3];
    const float* bk  = (const float*)d_in[4];
    const float* Wv  = (const float*)d_in[5];
    const float* bv  = (const float*)d_in[6];
    const float* g1  = (const float*)d_in[7];
    const float* be1 = (const float*)d_in[8];
    const float* W1  = (const float*)d_in[9];
    const float* b1  = (const float*)d_in[10];
    const float* W2  = (const float*)d_in[11];
    const float* b2  = (const float*)d_in[12];
    const float* g2  = (const float*)d_in[13];
    const float* be2 = (const float*)d_in[14];

    const int M = in_sizes[0] / 1024;        // 16384 tokens
    float* F    = (float*)d_out;             // fp32 pre-LN2 sum & final out (64 MB)
    short* xbf  = (short*)d_out;             // bf16 x, lower 32 MB (dead after QKV)
    short* Obf  = (short*)d_out + (size_t)M * 1024;  // bf16 attn O, upper 32 MB

    // workspace layout (bytes); peak 123,744,256
    char* ws = (char*)d_ws;
    short* WqkvT = (short*)ws;                     // [0, 6291456)
    short* W1T   = (short*)(ws + 6291456);         // [.., 14680064)
    short* W2T   = (short*)(ws + 14680064);        // [.., 23068672)
    float* bqkv  = (float*)(ws + 23068672);        // [.., 23080960)
    short* QKV   = (short*)(ws + 23080960);        // M x 3072 bf16 (96 MB)
    short* Hh    = (short*)(ws + 23080960);        // M x 2048 bf16, overlays QKV[0:64MB)
    short* x1    = (short*)(ws + 23080960 + (size_t)M * 2048 * 2); // M x 1024 bf16, QKV[64:96MB)

    dim3 blk(256);
    dim3 blk5(512);
    // weight prep (fp32 -> transposed bf16)
    transpose_kernel<<<dim3(16, 16), blk, 0, stream>>>(Wq, WqkvT,               1024, 1024);
    transpose_kernel<<<dim3(16, 16), blk, 0, stream>>>(Wk, WqkvT + 1024 * 1024, 1024, 1024);
    transpose_kernel<<<dim3(16, 16), blk, 0, stream>>>(Wv, WqkvT + 2048 * 1024, 1024, 1024);
    transpose_kernel<<<dim3(16, 64), blk, 0, stream>>>(W1, W1T, 1024, 4096);
    transpose_kernel<<<dim3(64, 16), blk, 0, stream>>>(W2, W2T, 4096, 1024);
    concat_bias_kernel<<<12, blk, 0, stream>>>(bq, bk, bv, bqkv);
    cvt_kernel<<<M, blk, 0, stream>>>(x, xbf);

    // QKV = x_bf @ Wqkv + bqkv  (bf16 out)
    gemm256_kernel<0, 0><<<dim3(M / 256, 12), blk5, 0, stream>>>(
        xbf, 1024, WqkvT, 1024, bqkv, QKV, 3072, M, 3072, 1024);
    // windowed attention (MFMA) -> O (d_out upper half; xbf now dead)
    attn_mfma_kernel<<<M / 64, blk, 0, stream>>>(QKV, Obf);
    // x1 = LN(x + O) -> bf16 in ws (QKV dead from here)
    ln1_kernel<<<M, blk, 0, stream>>>(x, Obf, g1, be1, x1);
    // FFN half a: Hh = relu(x1 @ W1[:, :2048]); F = Hh @ W2[:2048, :] + b2 (fp32)
    gemm256_kernel<1, 0><<<dim3(M / 256, 8), blk5, 0, stream>>>(
        x1, 1024, W1T, 1024, b1, Hh, 2048, M, 2048, 1024);
    gemm256_kernel<0, 1><<<dim3(M / 256, 4), blk5, 0, stream>>>(
        Hh, 2048, W2T, 4096, b2, F, 1024, M, 1024, 2048);
    // FFN half b: Hh = relu(x1 @ W1[:, 2048:]); F += Hh @ W2[2048:, :]
    gemm256_kernel<1, 0><<<dim3(M / 256, 8), blk5, 0, stream>>>(
        x1, 1024, W1T + 2048 * 1024, 1024, b1 + 2048, Hh, 2048, M, 2048, 1024);
    gemm256_kernel<0, 2><<<dim3(M / 256, 4), blk5, 0, stream>>>(
        Hh, 2048, W2T + 2048, 4096, b2, F, 1024, M, 1024, 2048);
    // out = LN(x1 + F) -> fp32, in place on F (= d_out)
    ln2_kernel<<<M, blk, 0, stream>>>(x1, F, g2, be2);
}

// Round 5
// 675.987 us; speedup vs baseline: 1.6416x; 1.0004x over previous
//
#include <hip/hip_runtime.h>
#include <hip/hip_bf16.h>
#include <stdint.h>

// WindowAttention block for MI355X (gfx950). Round 12 (= round 11 resubmit;
// round-11 bench died in the container broker with no measurement, same as
// round-8 -> round-9 precedent where identical resubmit passed).
// Round-10 post-mortem: 256^2 phased GEMM only hit 833 TF (MfmaUtil 35%).
// Cycle model: LDS reads (2304+768 conflict cyc/CU/tile) ~= MFMA (2483) and
// extra sched_barrier(0)s + 2 extra gate barriers serialized them (m141
// failure mode). This round: exact m201 cadence -- per phase {ds_read; stage;
// barrier; lgkmcnt(0)+SB0; setprio; 16 MFMA; setprio; [vmcnt(4) at ph2/ph4];
// barrier}. 8 barriers/K-tile, counted gates folded, no other SB(0).
// ws peak 123,744,256 B (<= 130 MB).

typedef __attribute__((ext_vector_type(4))) float f32x4;
typedef __attribute__((ext_vector_type(8))) short bf16x8;
typedef __attribute__((ext_vector_type(4))) short bf16x4;

__device__ __forceinline__ void async_cp16(const void* g, void* l) {
    __builtin_amdgcn_global_load_lds(
        (const __attribute__((address_space(1))) void*)g,
        (__attribute__((address_space(3))) void*)l,
        16, 0, 0);
}

__device__ __forceinline__ short f2bf(float f) {
    __hip_bfloat16 h = __float2bfloat16(f);
    return __builtin_bit_cast(short, h);
}
__device__ __forceinline__ float bf2f(short s) {
    return __bfloat162float(__builtin_bit_cast(__hip_bfloat16, s));
}

// ---------------- 256x256 8-wave phase-interleaved GEMM -------------------
// C[MxN] = A[MxK] * Bt[NxK]^T + bias. A, Bt bf16.
// MODE 0: C bf16 (+bias, optional RELU). MODE 1: C fp32 (+bias).
// MODE 2: C fp32 += acc.
// LDS (shorts): buf c at c*32768; A slab ksub at +ksub*8192 (256 rows x 32),
// B at +16384 likewise. Swizzle: short addr = (row*32 + quad*8) ^ ((row&7)<<3).
// Staging: linear global_load_lds dest; global source inverse-swizzled.
// Gate math (2 loads/thread/stage): staging order per iter kt (for kt+1):
// ph1:A0' ph2:B0' ph3:A1' ph4:B1'. ph2-end gate protects A1,B1 (issued kt-1
// ph3/4): outstanding <= {A1,B1,A0',B0'} = 8 loads -> vmcnt(4). ph4-end gate
// protects A0',B0': outstanding {A0',B0',A1',B1'} = 8 -> vmcnt(4). Last iter:
// ph2 -> vmcnt(0), ph4 -> none. Prologue: 4 stages, vmcnt(4), barrier.
template <int RELU, int MODE>
__global__ __launch_bounds__(512, 2) void gemm256_kernel(
    const short* __restrict__ A, int lda,
    const short* __restrict__ Bt, int ldb,
    const float* __restrict__ bias,
    void* __restrict__ Cv, int ldc,
    int M, int N, int K)
{
    __shared__ __align__(16) short lds[65536];   // 128 KB

    const int t = threadIdx.x;
    const int wave = t >> 6, lane = t & 63;
    const int quad = lane >> 4, l16 = lane & 15;
    const int wm = wave >> 2, wn = wave & 3;      // 2 x 4 wave grid
    const long m0 = (long)blockIdx.x * 256;
    const long n0 = (long)blockIdx.y * 256;

    // staging constants (inverse swizzle baked into the global source)
    const int srow = t >> 2;                      // 0..127
    const int sg = t & 3;
    const int lr0 = srow ^ ((srow >> 2) & 1);     // logical row
    const int lg0 = sg ^ (lr0 & 3);               // logical granule
    const short* gA = A + (m0 + lr0) * (long)lda + lg0 * 8;
    const short* gB = Bt + (n0 + lr0) * (long)ldb + lg0 * 8;
    const int wdst = wave * 512;                  // shorts, + j*4096

    // swizzled LDS read offsets (shorts, within a k-slab)
    int offA[8], offB[4];
#pragma unroll
    for (int mf = 0; mf < 8; ++mf) {
        const int row = wm * 128 + mf * 16 + l16;
        offA[mf] = (row * 32 + quad * 8) ^ ((row & 7) << 3);
    }
#pragma unroll
    for (int nf = 0; nf < 4; ++nf) {
        const int row = wn * 64 + nf * 16 + l16;
        offB[nf] = (row * 32 + quad * 8) ^ ((row & 7) << 3);
    }

    f32x4 acc[8][4] = {};
    const int NT = K >> 6;

#define STAGE_A(ksub, kt, buf)                                                 \
    do {                                                                       \
        const int ko_ = (kt) * 64 + (ksub) * 32;                               \
        short* d_ = lds + (buf) * 32768 + (ksub) * 8192 + wdst;                \
        async_cp16(gA + ko_, d_);                                              \
        async_cp16(gA + 128 * (long)lda + ko_, d_ + 4096);                     \
    } while (0)
#define STAGE_B(ksub, kt, buf)                                                 \
    do {                                                                       \
        const int ko_ = (kt) * 64 + (ksub) * 32;                               \
        short* d_ = lds + (buf) * 32768 + 16384 + (ksub) * 8192 + wdst;        \
        async_cp16(gB + ko_, d_);                                              \
        async_cp16(gB + 128 * (long)ldb + ko_, d_ + 4096);                     \
    } while (0)

    // prologue: stage tile 0; gate A0,B0 (leave A1,B1 in flight)
    STAGE_A(0, 0, 0); STAGE_B(0, 0, 0); STAGE_A(1, 0, 0); STAGE_B(1, 0, 0);
    asm volatile("s_waitcnt vmcnt(4)" ::: "memory");
    __builtin_amdgcn_s_barrier();

    for (int kt = 0; kt < NT; ++kt) {
        const int cbuf = kt & 1, nbuf = cbuf ^ 1;
        const short* Ab = lds + cbuf * 32768;
        const short* Bb = Ab + 16384;
        const bool more = (kt + 1 < NT);

        bf16x8 av[4], bv[4];

        // ===== phase 1: ksub0, mf 0-3 =====
#pragma unroll
        for (int nf = 0; nf < 4; ++nf) bv[nf] = *(const bf16x8*)(Bb + offB[nf]);
#pragma unroll
        for (int i = 0; i < 4; ++i) av[i] = *(const bf16x8*)(Ab + offA[i]);
        if (more) STAGE_A(0, kt + 1, nbuf);
        __builtin_amdgcn_s_barrier();
        asm volatile("s_waitcnt lgkmcnt(0)" ::: "memory");
        __builtin_amdgcn_sched_barrier(0);
        __builtin_amdgcn_s_setprio(1);
#pragma unroll
        for (int i = 0; i < 4; ++i)
#pragma unroll
            for (int nf = 0; nf < 4; ++nf)
                acc[i][nf] = __builtin_amdgcn_mfma_f32_16x16x32_bf16(
                    av[i], bv[nf], acc[i][nf], 0, 0, 0);
        __builtin_amdgcn_s_setprio(0);
        __builtin_amdgcn_s_barrier();

        // ===== phase 2: ksub0, mf 4-7 =====
#pragma unroll
        for (int i = 0; i < 4; ++i) av[i] = *(const bf16x8*)(Ab + offA[4 + i]);
        if (more) STAGE_B(0, kt + 1, nbuf);
        __builtin_amdgcn_s_barrier();
        asm volatile("s_waitcnt lgkmcnt(0)" ::: "memory");
        __builtin_amdgcn_sched_barrier(0);
        __builtin_amdgcn_s_setprio(1);
#pragma unroll
        for (int i = 0; i < 4; ++i)
#pragma unroll
            for (int nf = 0; nf < 4; ++nf)
                acc[4 + i][nf] = __builtin_amdgcn_mfma_f32_16x16x32_bf16(
                    av[i], bv[nf], acc[4 + i][nf], 0, 0, 0);
        __builtin_amdgcn_s_setprio(0);
        if (more) asm volatile("s_waitcnt vmcnt(4)" ::: "memory");
        else      asm volatile("s_waitcnt vmcnt(0)" ::: "memory");
        __builtin_amdgcn_s_barrier();

        // ===== phase 3: ksub1, mf 0-3 =====
#pragma unroll
        for (int nf = 0; nf < 4; ++nf) bv[nf] = *(const bf16x8*)(Bb + 8192 + offB[nf]);
#pragma unroll
        for (int i = 0; i < 4; ++i) av[i] = *(const bf16x8*)(Ab + 8192 + offA[i]);
        if (more) STAGE_A(1, kt + 1, nbuf);
        __builtin_amdgcn_s_barrier();
        asm volatile("s_waitcnt lgkmcnt(0)" ::: "memory");
        __builtin_amdgcn_sched_barrier(0);
        __builtin_amdgcn_s_setprio(1);
#pragma unroll
        for (int i = 0; i < 4; ++i)
#pragma unroll
            for (int nf = 0; nf < 4; ++nf)
                acc[i][nf] = __builtin_amdgcn_mfma_f32_16x16x32_bf16(
                    av[i], bv[nf], acc[i][nf], 0, 0, 0);
        __builtin_amdgcn_s_setprio(0);
        __builtin_amdgcn_s_barrier();

        // ===== phase 4: ksub1, mf 4-7 =====
#pragma unroll
        for (int i = 0; i < 4; ++i) av[i] = *(const bf16x8*)(Ab + 8192 + offA[4 + i]);
        if (more) STAGE_B(1, kt + 1, nbuf);
        __builtin_amdgcn_s_barrier();
        asm volatile("s_waitcnt lgkmcnt(0)" ::: "memory");
        __builtin_amdgcn_sched_barrier(0);
        __builtin_amdgcn_s_setprio(1);
#pragma unroll
        for (int i = 0; i < 4; ++i)
#pragma unroll
            for (int nf = 0; nf < 4; ++nf)
                acc[4 + i][nf] = __builtin_amdgcn_mfma_f32_16x16x32_bf16(
                    av[i], bv[nf], acc[4 + i][nf], 0, 0, 0);
        __builtin_amdgcn_s_setprio(0);
        if (more) {
            asm volatile("s_waitcnt vmcnt(4)" ::: "memory");
            __builtin_amdgcn_s_barrier();
        }
    }
#undef STAGE_A
#undef STAGE_B

    // epilogue
#pragma unroll
    for (int mf = 0; mf < 8; ++mf) {
#pragma unroll
        for (int nf = 0; nf < 4; ++nf) {
            const int n = (int)n0 + wn * 64 + nf * 16 + l16;
            const float bz = (MODE == 2) ? 0.f : bias[n];
#pragma unroll
            for (int r = 0; r < 4; ++r) {
                const long m = m0 + wm * 128 + mf * 16 + quad * 4 + r;
                float v = acc[mf][nf][r] + bz;
                if (MODE == 0) {
                    if (RELU) v = fmaxf(v, 0.f);
                    ((short*)Cv)[m * ldc + n] = f2bf(v);
                } else if (MODE == 1) {
                    ((float*)Cv)[m * ldc + n] = v;
                } else {
                    ((float*)Cv)[m * ldc + n] += v;   // own element, race-free
                }
            }
        }
    }
}

// -------- MFMA windowed attention: one block (4 waves) per 64-token window -
__global__ __launch_bounds__(256) void attn_mfma_kernel(
    const short* __restrict__ QKV, short* __restrict__ O)
{
    __shared__ __align__(16) float Sf[64 * 65];    // 16640 B
    __shared__ __align__(16) short Pb[64 * 72];    //  9216 B
    __shared__ __align__(16) short Vt[256 * 72];   // 36864 B   (tot 62720)

    const int t = threadIdx.x;
    const int wave = t >> 6, lane = t & 63;
    const int quad = lane >> 4, l16 = lane & 15;
    const long rowbase = (long)blockIdx.x * 64;
    const short* Qg = QKV + rowbase * 3072;
    const short* Kg = Qg + 1024;
    const short* Vg = Qg + 2048;

    // ---------------- phase A: scores ----------------
    {
        const int wy = wave >> 1, wx = wave & 1;
        const short* qp0 = Qg + (long)(wy * 32 + l16) * 3072 + quad * 8;
        const short* qp1 = qp0 + 16 * 3072;
        const short* kp0 = Kg + (long)(wx * 32 + l16) * 3072 + quad * 8;
        const short* kp1 = kp0 + 16 * 3072;

        f32x4 s00 = {}, s01 = {}, s10 = {}, s11 = {};
        bf16x8 a0 = *(const bf16x8*)qp0;
        bf16x8 a1 = *(const bf16x8*)qp1;
        bf16x8 b0 = *(const bf16x8*)kp0;
        bf16x8 b1 = *(const bf16x8*)kp1;

#pragma unroll 2
        for (int k0 = 0; k0 < 1024; k0 += 32) {
            const int kn = (k0 + 32 < 1024) ? k0 + 32 : 0;  // clamp (dummy reload)
            bf16x8 na0 = *(const bf16x8*)(qp0 + kn);
            bf16x8 na1 = *(const bf16x8*)(qp1 + kn);
            bf16x8 nb0 = *(const bf16x8*)(kp0 + kn);
            bf16x8 nb1 = *(const bf16x8*)(kp1 + kn);
            s00 = __builtin_amdgcn_mfma_f32_16x16x32_bf16(a0, b0, s00, 0, 0, 0);
            s01 = __builtin_amdgcn_mfma_f32_16x16x32_bf16(a0, b1, s01, 0, 0, 0);
            s10 = __builtin_amdgcn_mfma_f32_16x16x32_bf16(a1, b0, s10, 0, 0, 0);
            s11 = __builtin_amdgcn_mfma_f32_16x16x32_bf16(a1, b1, s11, 0, 0, 0);
            a0 = na0; a1 = na1; b0 = nb0; b1 = nb1;
        }

        const int rb = wy * 32 + quad * 4;
        const int cb = wx * 32 + l16;
#pragma unroll
        for (int r = 0; r < 4; ++r) {
            Sf[(rb + r) * 65 + cb]           = s00[r] * 0.03125f;
            Sf[(rb + r) * 65 + cb + 16]      = s01[r] * 0.03125f;
            Sf[(rb + 16 + r) * 65 + cb]      = s10[r] * 0.03125f;
            Sf[(rb + 16 + r) * 65 + cb + 16] = s11[r] * 0.03125f;
        }
    }
    __syncthreads();

    // ---------------- phase B: softmax (4 threads per row) ----------------
    {
        const int row = t >> 2;
        const int cs = (t & 3) * 16;
        const float* sp = Sf + row * 65 + cs;
        float v[16];
        float mx = -1e30f;
#pragma unroll
        for (int j = 0; j < 16; ++j) { v[j] = sp[j]; mx = fmaxf(mx, v[j]); }
        mx = fmaxf(mx, __shfl_xor(mx, 1, 64));
        mx = fmaxf(mx, __shfl_xor(mx, 2, 64));
        float sum = 0.f;
#pragma unroll
        for (int j = 0; j < 16; ++j) { v[j] = __expf(v[j] - mx); sum += v[j]; }
        sum += __shfl_xor(sum, 1, 64);
        sum += __shfl_xor(sum, 2, 64);
        const float inv = 1.f / sum;
        short* pp = Pb + row * 72 + cs;
        bf16x8 o0, o1;
#pragma unroll
        for (int j = 0; j < 8; ++j) { o0[j] = f2bf(v[j] * inv); o1[j] = f2bf(v[8 + j] * inv); }
        *(bf16x8*)(pp) = o0;
        *(bf16x8*)(pp + 8) = o1;
    }
    __syncthreads();

    // ---------------- phase C: O = P.V, 256-col chunks ----------------
    bf16x8 am[2][4];
#pragma unroll
    for (int ki = 0; ki < 2; ++ki)
#pragma unroll
        for (int mi = 0; mi < 4; ++mi)
            am[ki][mi] = *(const bf16x8*)(Pb + (mi * 16 + l16) * 72 + ki * 32 + quad * 8);

    for (int nc = 0; nc < 4; ++nc) {
        const int nbase = nc * 256;
#pragma unroll
        for (int it = 0; it < 8; ++it) {
            const int idx = it * 256 + t;          // 0..2047
            const int tok = idx >> 5;              // 0..63
            const int grp = idx & 31;              // e-group of 8
            bf16x8 v = *(const bf16x8*)(Vg + (long)tok * 3072 + nbase + grp * 8);
            const int tsw = tok ^ ((grp & 7) << 3);  // bank swizzle
            short* dst = Vt + (grp * 8) * 72 + tsw;
#pragma unroll
            for (int j = 0; j < 8; ++j) dst[j * 72] = v[j];
        }
        __syncthreads();

        f32x4 acc[4][4] = {};
#pragma unroll
        for (int ki = 0; ki < 2; ++ki) {
            bf16x8 bn[4];
#pragma unroll
            for (int ni = 0; ni < 4; ++ni) {
                const int e_local = wave * 64 + ni * 16 + l16;
                const int s = (e_local >> 3) & 7;
                bn[ni] = *(const bf16x8*)(Vt + e_local * 72 + ((ki * 32 + quad * 8) ^ (s << 3)));
            }
#pragma unroll
            for (int mi = 0; mi < 4; ++mi)
#pragma unroll
                for (int ni = 0; ni < 4; ++ni)
                    acc[mi][ni] = __builtin_amdgcn_mfma_f32_16x16x32_bf16(
                        am[ki][mi], bn[ni], acc[mi][ni], 0, 0, 0);
        }

#pragma unroll
        for (int mi = 0; mi < 4; ++mi)
#pragma unroll
            for (int ni = 0; ni < 4; ++ni) {
                const long n = nbase + wave * 64 + ni * 16 + l16;
#pragma unroll
                for (int r = 0; r < 4; ++r) {
                    const long m = rowbase + mi * 16 + quad * 4 + r;
                    O[m * 1024 + n] = f2bf(acc[mi][ni][r]);
                }
            }
        __syncthreads();   // Vt reused next chunk
    }
}

// ------------- LN1: x1 = LN(x_fp32 + O_bf16) * g + b -> bf16 --------------
__global__ __launch_bounds__(256, 4) void ln1_kernel(
    const float* __restrict__ X, const short* __restrict__ R,
    const float* __restrict__ gamma, const float* __restrict__ beta,
    short* __restrict__ Y)
{
    __shared__ float red[8];
    const int t = threadIdx.x;
    const int wave = t >> 6, lane = t & 63;
    const long row = blockIdx.x;

    f32x4 xv = *(const f32x4*)(X + row * 1024 + t * 4);
    bf16x4 rv = *(const bf16x4*)(R + row * 1024 + t * 4);
    float v[4];
    float s = 0.f, sq = 0.f;
#pragma unroll
    for (int i = 0; i < 4; ++i) {
        v[i] = xv[i] + bf2f(rv[i]);
        s += v[i];
        sq += v[i] * v[i];
    }
#pragma unroll
    for (int off = 32; off > 0; off >>= 1) {
        s  += __shfl_down(s, off, 64);
        sq += __shfl_down(sq, off, 64);
    }
    if (lane == 0) { red[wave] = s; red[4 + wave] = sq; }
    __syncthreads();
    if (t == 0) {
        float S = red[0] + red[1] + red[2] + red[3];
        float Q = red[4] + red[5] + red[6] + red[7];
        float mean = S * (1.f / 1024.f);
        float var = fmaxf(Q * (1.f / 1024.f) - mean * mean, 0.f);
        red[0] = mean;
        red[1] = rsqrtf(var + 1e-5f);
    }
    __syncthreads();
    const float mean = red[0], rstd = red[1];
    f32x4 gv = *(const f32x4*)(gamma + t * 4);
    f32x4 bv = *(const f32x4*)(beta + t * 4);
    bf16x4 yv;
#pragma unroll
    for (int i = 0; i < 4; ++i)
        yv[i] = f2bf((v[i] - mean) * rstd * gv[i] + bv[i]);
    *(bf16x4*)(Y + row * 1024 + t * 4) = yv;
}

// ------ LN2: out = LN(x1_bf16 + F_fp32) * g + b -> fp32, in place on F ----
__global__ __launch_bounds__(256, 4) void ln2_kernel(
    const short* __restrict__ X1, float* __restrict__ F,
    const float* __restrict__ gamma, const float* __restrict__ beta)
{
    __shared__ float red[8];
    const int t = threadIdx.x;
    const int wave = t >> 6, lane = t & 63;
    const long row = blockIdx.x;

    bf16x4 xv = *(const bf16x4*)(X1 + row * 1024 + t * 4);
    f32x4 fv = *(const f32x4*)(F + row * 1024 + t * 4);
    float v[4];
    float s = 0.f, sq = 0.f;
#pragma unroll
    for (int i = 0; i < 4; ++i) {
        v[i] = bf2f(xv[i]) + fv[i];
        s += v[i];
        sq += v[i] * v[i];
    }
#pragma unroll
    for (int off = 32; off > 0; off >>= 1) {
        s  += __shfl_down(s, off, 64);
        sq += __shfl_down(sq, off, 64);
    }
    if (lane == 0) { red[wave] = s; red[4 + wave] = sq; }
    __syncthreads();
    if (t == 0) {
        float S = red[0] + red[1] + red[2] + red[3];
        float Q = red[4] + red[5] + red[6] + red[7];
        float mean = S * (1.f / 1024.f);
        float var = fmaxf(Q * (1.f / 1024.f) - mean * mean, 0.f);
        red[0] = mean;
        red[1] = rsqrtf(var + 1e-5f);
    }
    __syncthreads();
    const float mean = red[0], rstd = red[1];
    f32x4 gv = *(const f32x4*)(gamma + t * 4);
    f32x4 bv = *(const f32x4*)(beta + t * 4);
    f32x4 yv;
#pragma unroll
    for (int i = 0; i < 4; ++i)
        yv[i] = (v[i] - mean) * rstd * gv[i] + bv[i];
    *(f32x4*)(F + row * 1024 + t * 4) = yv;   // own row: in-place safe
}

// --------- weight transpose + cast: W[KxN] fp32 -> WT[NxK] bf16 -----------
__global__ __launch_bounds__(256, 2) void transpose_kernel(
    const float* __restrict__ W, short* __restrict__ WT, int K, int N)
{
    __shared__ __align__(16) short tile[64 * 72];
    const int t = threadIdx.x;
    const long kb = (long)blockIdx.x * 64, nb = (long)blockIdx.y * 64;
    const int r = t >> 3, c = (t & 7) << 3;
#pragma unroll
    for (int i = 0; i < 2; ++i) {
        f32x4 v0 = *(const f32x4*)(W + (kb + r + i * 32) * N + nb + c);
        f32x4 v1 = *(const f32x4*)(W + (kb + r + i * 32) * N + nb + c + 4);
        short* dst = tile + (r + i * 32) * 72 + c;
#pragma unroll
        for (int j = 0; j < 4; ++j) { dst[j] = f2bf(v0[j]); dst[4 + j] = f2bf(v1[j]); }
    }
    __syncthreads();
#pragma unroll
    for (int i = 0; i < 2; ++i) {
        const int rr = r + i * 32;      // n-index within tile
        bf16x8 o;
#pragma unroll
        for (int j = 0; j < 8; ++j) o[j] = tile[(c + j) * 72 + rr];
        *(bf16x8*)(WT + (nb + rr) * K + kb + c) = o;
    }
}

// --------------- x fp32 -> bf16 (into d_out lower half) -------------------
__global__ __launch_bounds__(256, 4) void cvt_kernel(
    const float* __restrict__ X, short* __restrict__ Y)
{
    const long i = ((long)blockIdx.x * 256 + threadIdx.x) * 4;
    f32x4 v = *(const f32x4*)(X + i);
    bf16x4 o;
#pragma unroll
    for (int j = 0; j < 4; ++j) o[j] = f2bf(v[j]);
    *(bf16x4*)(Y + i) = o;
}

__global__ void concat_bias_kernel(const float* __restrict__ bq,
                                   const float* __restrict__ bk,
                                   const float* __restrict__ bv,
                                   float* __restrict__ out)
{
    const int i = blockIdx.x * 256 + threadIdx.x;   // 0..3071
    float v;
    if (i < 1024)      v = bq[i];
    else if (i < 2048) v = bk[i - 1024];
    else               v = bv[i - 2048];
    out[i] = v;
}

extern "C" void kernel_launch(void* const* d_in, const int* in_sizes, int n_in,
                              void* d_out, int out_size, void* d_ws, size_t ws_size,
                              hipStream_t stream)
{
    const float* x   = (const float*)d_in[0];
    const float* Wq  = (const float*)d_in[1];
    const float* bq  = (const float*)d_in[2];
    const float* Wk  = (const float*)d_in[3];
    const float* bk  = (const float*)d_in[4];
    const float* Wv  = (const float*)d_in[5];
    const float* bv  = (const float*)d_in[6];
    const float* g1  = (const float*)d_in[7];
    const float* be1 = (const float*)d_in[8];
    const float* W1  = (const float*)d_in[9];
    const float* b1  = (const float*)d_in[10];
    const float* W2  = (const float*)d_in[11];
    const float* b2  = (const float*)d_in[12];
    const float* g2  = (const float*)d_in[13];
    const float* be2 = (const float*)d_in[14];

    const int M = in_sizes[0] / 1024;        // 16384 tokens
    float* F    = (float*)d_out;             // fp32 pre-LN2 sum & final out (64 MB)
    short* xbf  = (short*)d_out;             // bf16 x, lower 32 MB (dead after QKV)
    short* Obf  = (short*)d_out + (size_t)M * 1024;  // bf16 attn O, upper 32 MB

    // workspace layout (bytes); peak 123,744,256
    char* ws = (char*)d_ws;
    short* WqkvT = (short*)ws;                     // [0, 6291456)
    short* W1T   = (short*)(ws + 6291456);         // [.., 14680064)
    short* W2T   = (short*)(ws + 14680064);        // [.., 23068672)
    float* bqkv  = (float*)(ws + 23068672);        // [.., 23080960)
    short* QKV   = (short*)(ws + 23080960);        // M x 3072 bf16 (96 MB)
    short* Hh    = (short*)(ws + 23080960);        // M x 2048 bf16, overlays QKV[0:64MB)
    short* x1    = (short*)(ws + 23080960 + (size_t)M * 2048 * 2); // M x 1024 bf16, QKV[64:96MB)

    dim3 blk(256);
    dim3 blk5(512);
    // weight prep (fp32 -> transposed bf16)
    transpose_kernel<<<dim3(16, 16), blk, 0, stream>>>(Wq, WqkvT,               1024, 1024);
    transpose_kernel<<<dim3(16, 16), blk, 0, stream>>>(Wk, WqkvT + 1024 * 1024, 1024, 1024);
    transpose_kernel<<<dim3(16, 16), blk, 0, stream>>>(Wv, WqkvT + 2048 * 1024, 1024, 1024);
    transpose_kernel<<<dim3(16, 64), blk, 0, stream>>>(W1, W1T, 1024, 4096);
    transpose_kernel<<<dim3(64, 16), blk, 0, stream>>>(W2, W2T, 4096, 1024);
    concat_bias_kernel<<<12, blk, 0, stream>>>(bq, bk, bv, bqkv);
    cvt_kernel<<<M, blk, 0, stream>>>(x, xbf);

    // QKV = x_bf @ Wqkv + bqkv  (bf16 out)
    gemm256_kernel<0, 0><<<dim3(M / 256, 12), blk5, 0, stream>>>(
        xbf, 1024, WqkvT, 1024, bqkv, QKV, 3072, M, 3072, 1024);
    // windowed attention (MFMA) -> O (d_out upper half; xbf now dead)
    attn_mfma_kernel<<<M / 64, blk, 0, stream>>>(QKV, Obf);
    // x1 = LN(x + O) -> bf16 in ws (QKV dead from here)
    ln1_kernel<<<M, blk, 0, stream>>>(x, Obf, g1, be1, x1);
    // FFN half a: Hh = relu(x1 @ W1[:, :2048]); F = Hh @ W2[:2048, :] + b2 (fp32)
    gemm256_kernel<1, 0><<<dim3(M / 256, 8), blk5, 0, stream>>>(
        x1, 1024, W1T, 1024, b1, Hh, 2048, M, 2048, 1024);
    gemm256_kernel<0, 1><<<dim3(M / 256, 4), blk5, 0, stream>>>(
        Hh, 2048, W2T, 4096, b2, F, 1024, M, 1024, 2048);
    // FFN half b: Hh = relu(x1 @ W1[:, 2048:]); F += Hh @ W2[2048:, :]
    gemm256_kernel<1, 0><<<dim3(M / 256, 8), blk5, 0, stream>>>(
        x1, 1024, W1T + 2048 * 1024, 1024, b1 + 2048, Hh, 2048, M, 2048, 1024);
    gemm256_kernel<0, 2><<<dim3(M / 256, 4), blk5, 0, stream>>>(
        Hh, 2048, W2T + 2048, 4096, b2, F, 1024, M, 1024, 2048);
    // out = LN(x1 + F) -> fp32, in place on F (= d_out)
    ln2_kernel<<<M, blk, 0, stream>>>(x1, F, g2, be2);
}